// Round 6
// baseline (176.205 us; speedup 1.0000x reference)
//
#include <hip/hip_runtime.h>

// PositionWiseSpatialAttention — fused flash-style, MI355X gfx950.  R6.
//
// R5 counters: VALU 36.5 / MFMA 29.3 / HBM 15% / occ 27% -> latency-bound on
// the P LDS round-trip (16 ds_write + lgkm + 4 ds_read per wave-tile) and the
// epilogue AG round-trip (+2 barriers).  R6 restructure:
//  * compute S^T = K.Q^T with 32x32x16 MFMA: C col = lane&31 = QUERY.  Then
//    P^T (key-major) -> PV^T B-frag needs only a half-wave exchange
//    (shfl_xor 32) of packed bf16 pairs -- no LDS, no barrier.
//  * same trick for agg^T -> epilogue B-frag: epilogue is barrier/LDS-free.
//  * adj + output become dwordx4 per lane; denominator is 1 scalar/lane.
//  * LDS: only K/V staging (19456 B).  3-term split bf16 everywhere (~fp32).
// Layouts: C/D 32x32: col=lane&31, row=(reg&3)+8*(reg>>2)+4*(lane>>5)
// [HW-verified m74/m101].  A: m=lane&31, k=(lane>>5)*8+j; B symmetric.

#define NB    8
#define NT    12
#define NNODE 1024
#define ND    64
#define XROW  768   /* NT*ND */

typedef __bf16 bf16x8  __attribute__((ext_vector_type(8)));
typedef __bf16 bf16x2  __attribute__((ext_vector_type(2)));
typedef float  floatx4 __attribute__((ext_vector_type(4)));
typedef float  floatx16 __attribute__((ext_vector_type(16)));
typedef unsigned uintx4 __attribute__((ext_vector_type(4)));

#define MFMA32(a,b,c) __builtin_amdgcn_mfma_f32_32x32x16_bf16((a),(b),(c),0,0,0)
#define QSCALE 0.18033688011112042f   /* 0.125 * log2(e) */

#define KSTRIDE 72   /* bf16 per K row (d-major), 144 B */
#define VSTRIDE 40   /* bf16 per V row (key-major), 80 B */
#define OFF_KHI 0
#define OFF_KLO 4608
#define OFF_VHI 9216
#define OFF_VLO 14336
#define SMEM_BYTES 19456

struct bfpair { __bf16 h, l; };

// error-compensated split: hi = RNE(f), lo = RNE(f - hi); err ~ 2^-17 |f|
__device__ __forceinline__ bfpair split1(float f) {
    bfpair r;
    __bf16 hb = (__bf16)f;
    float hf = __builtin_bit_cast(float,
                   (unsigned)__builtin_bit_cast(unsigned short, hb) << 16);
    r.h = hb;
    r.l = (__bf16)(f - hf);
    return r;
}

__device__ __forceinline__ unsigned pk2(__bf16 a, __bf16 b) {
    bf16x2 t; t[0] = a; t[1] = b;
    return __builtin_bit_cast(unsigned, t);
}

// Half-wave exchange assembling a B-frag (k = (lane>>5)*8+j) from C-layout
// packed pairs.  A0,A1 = group 2kc (regs 0..3 as 2 u32), B0,B1 = group 2kc+1.
// Lower half (L5=0) keeps A for j0..3 and pulls partner's A for j4..7; upper
// half pulls partner's B for j0..3 and keeps its B for j4..7.
__device__ __forceinline__ bf16x8 xchg(unsigned A0, unsigned A1,
                                       unsigned B0, unsigned B1, int L5) {
    unsigned sA = L5 ? A0 : B0;
    unsigned sB = L5 ? A1 : B1;
    unsigned rA = (unsigned)__shfl_xor((int)sA, 32);
    unsigned rB = (unsigned)__shfl_xor((int)sB, 32);
    uintx4 u;
    u[0] = L5 ? rA : A0;
    u[1] = L5 ? rB : A1;
    u[2] = L5 ? B0 : rA;
    u[3] = L5 ? B1 : rB;
    return __builtin_bit_cast(bf16x8, u);
}

__global__ void __launch_bounds__(256, 2)
spattn(const float* __restrict__ x, const float* __restrict__ adj,
       const float* __restrict__ theta, float* __restrict__ out)
{
    __shared__ __align__(16) char smem[SMEM_BYTES];
    __bf16* Khi = (__bf16*)(smem + OFF_KHI);
    __bf16* Klo = (__bf16*)(smem + OFF_KLO);
    __bf16* Vhi = (__bf16*)(smem + OFF_VHI);
    __bf16* Vlo = (__bf16*)(smem + OFF_VLO);

    const int tid  = threadIdx.x;
    const int wave = tid >> 6;
    const int lane = tid & 63;
    const int q31  = lane & 31;
    const int L5   = lane >> 5;

    const int bx   = blockIdx.x;
    const int g    = bx >> 3;
    const int rblk = bx & 7;
    const int bb   = g / NT;
    const int tt   = g - bb * NT;
    const int row0 = rblk * 128;
    const int wq   = wave * 32;
    const int qglob = row0 + wq + q31;     // this lane's query row

    const float* xbase = x + (size_t)bb * (NNODE * XROW) + tt * ND;

    // ---- Q B-frags (hi/lo), pre-scaled; B[k=d][n=q]: lane holds
    // Q[qglob][d = dc*16 + L5*8 + j] ----
    bf16x8 qh[4], ql[4];
    {
        const float* qsrc = xbase + (size_t)qglob * XROW;
        #pragma unroll
        for (int dc = 0; dc < 4; ++dc) {
            floatx4 f0 = *(const floatx4*)(qsrc + dc*16 + L5*8);
            floatx4 f1 = *(const floatx4*)(qsrc + dc*16 + L5*8 + 4);
            #pragma unroll
            for (int i = 0; i < 4; ++i) {
                bfpair p0 = split1(f0[i]*QSCALE);
                qh[dc][i]   = p0.h; ql[dc][i]   = p0.l;
                bfpair p1 = split1(f1[i]*QSCALE);
                qh[dc][4+i] = p1.h; ql[dc][4+i] = p1.l;
            }
        }
    }

    floatx16 O0 = {}, O1 = {};   // O^T accum: d-tiles 0-31 / 32-63, col=q
    float lpart = 0.f;

    // staging maps (same as R5): K[key][d] 1x8-d, V[d][key] 1x8-key
    const int skey = tid >> 3;
    const int sd0  = (tid & 7) * 8;
    const int svd  = tid >> 2;
    const int svk0 = (tid & 3) * 8;
    floatx4 kf0, kf1;
    float vf[8];

    {
        const float* ksrc = xbase + (size_t)skey * XROW + sd0;
        kf0 = *(const floatx4*)ksrc;
        kf1 = *(const floatx4*)(ksrc + 4);
        const float* vsrc = xbase + (size_t)svk0 * XROW + svd;
        #pragma unroll
        for (int i = 0; i < 8; ++i) vf[i] = vsrc[i * XROW];
    }

    for (int ct = 0; ct < 32; ++ct) {
        const int key0 = ct * 32;
        __syncthreads();                       // prior tile reads done
        {
            bf16x8 h, l;
            #pragma unroll
            for (int i = 0; i < 4; ++i) {
                bfpair p0 = split1(kf0[i]); h[i]   = p0.h; l[i]   = p0.l;
                bfpair p1 = split1(kf1[i]); h[4+i] = p1.h; l[4+i] = p1.l;
            }
            *(bf16x8*)(Khi + skey*KSTRIDE + sd0) = h;
            *(bf16x8*)(Klo + skey*KSTRIDE + sd0) = l;
            bf16x8 vh, vl;
            #pragma unroll
            for (int i = 0; i < 8; ++i) {
                bfpair p = split1(vf[i]); vh[i] = p.h; vl[i] = p.l;
            }
            *(bf16x8*)(Vhi + svd*VSTRIDE + svk0) = vh;
            *(bf16x8*)(Vlo + svd*VSTRIDE + svk0) = vl;
        }
        __syncthreads();                       // staging visible
        if (ct < 31) {                         // register prefetch next tile
            const int nk = key0 + 32;
            const float* ksrc = xbase + (size_t)(nk + skey) * XROW + sd0;
            kf0 = *(const floatx4*)ksrc;
            kf1 = *(const floatx4*)(ksrc + 4);
            const float* vsrc = xbase + (size_t)(nk + svk0) * XROW + svd;
            #pragma unroll
            for (int i = 0; i < 8; ++i) vf[i] = vsrc[i * XROW];
        }
        // adj for this lane's query, keys key0 + rg*8 + L5*4 + 0..3
        floatx4 adjv[4];
        #pragma unroll
        for (int rg = 0; rg < 4; ++rg)
            adjv[rg] = *(const floatx4*)(adj + (size_t)qglob * NNODE
                                         + key0 + rg*8 + L5*4);

        // ---- S^T = K.Q^T (A = K-frag: m=key, k=d), one 32x32 C-frag ----
        floatx16 ST = {};
        #pragma unroll
        for (int dc = 0; dc < 4; ++dc) {
            bf16x8 kh = *(const bf16x8*)(Khi + q31*KSTRIDE + dc*16 + L5*8);
            bf16x8 kl = *(const bf16x8*)(Klo + q31*KSTRIDE + dc*16 + L5*8);
            ST = MFMA32(kh, qh[dc], ST);
            ST = MFMA32(kl, qh[dc], ST);
            ST = MFMA32(kh, ql[dc], ST);
        }
        // ---- P^T = adj*exp2(S^T): reg r -> key (r&3)+8*(r>>2)+4*L5 ----
        __bf16 pth[16], ptl[16];
        #pragma unroll
        for (int r = 0; r < 16; ++r) {
            float w = __builtin_amdgcn_exp2f(ST[r]);
            lpart += w;
            bfpair p = split1(adjv[r >> 2][r & 3] * w);
            pth[r] = p.h; ptl[r] = p.l;
        }
        // pack C-reg pairs per group (regs 4g..4g+3 -> 2 u32)
        unsigned GH[4][2], GL[4][2];
        #pragma unroll
        for (int gg = 0; gg < 4; ++gg) {
            GH[gg][0] = pk2(pth[4*gg],   pth[4*gg+1]);
            GH[gg][1] = pk2(pth[4*gg+2], pth[4*gg+3]);
            GL[gg][0] = pk2(ptl[4*gg],   ptl[4*gg+1]);
            GL[gg][1] = pk2(ptl[4*gg+2], ptl[4*gg+3]);
        }
        // ---- O^T += V^T . P^T  (A = V-frag: m=d, k=key) ----
        #pragma unroll
        for (int kc = 0; kc < 2; ++kc) {
            bf16x8 bh = xchg(GH[2*kc][0], GH[2*kc][1],
                             GH[2*kc+1][0], GH[2*kc+1][1], L5);
            bf16x8 bl = xchg(GL[2*kc][0], GL[2*kc][1],
                             GL[2*kc+1][0], GL[2*kc+1][1], L5);
            {
                bf16x8 vh = *(const bf16x8*)(Vhi + q31*VSTRIDE + kc*16 + L5*8);
                bf16x8 vl = *(const bf16x8*)(Vlo + q31*VSTRIDE + kc*16 + L5*8);
                O0 = MFMA32(vh, bh, O0);
                O0 = MFMA32(vl, bh, O0);
                O0 = MFMA32(vh, bl, O0);
            }
            {
                bf16x8 vh = *(const bf16x8*)(Vhi + (32+q31)*VSTRIDE + kc*16 + L5*8);
                bf16x8 vl = *(const bf16x8*)(Vlo + (32+q31)*VSTRIDE + kc*16 + L5*8);
                O1 = MFMA32(vh, bh, O1);
                O1 = MFMA32(vl, bh, O1);
                O1 = MFMA32(vh, bl, O1);
            }
        }
    }

    // ---- denominator: this lane holds half the keys for query q ----
    float l = lpart + __shfl_xor(lpart, 32);
    float linv = 1.0f / l;

    // ---- epilogue: out^T = theta^T . (O^T * linv), relu; LDS/barrier-free --
    // theta A-frags: A[m=o][k=d]: theta[d = kc*16+L5*8+j][o = ot*32+q31]
    bf16x8 th[2][4], tlo[2][4];
    #pragma unroll
    for (int ot = 0; ot < 2; ++ot)
        #pragma unroll
        for (int kc = 0; kc < 4; ++kc)
            #pragma unroll
            for (int j = 0; j < 8; ++j) {
                float tv = theta[(size_t)(kc*16 + L5*8 + j) * ND + ot*32 + q31];
                bfpair p = split1(tv);
                th[ot][kc][j] = p.h; tlo[ot][kc][j] = p.l;
            }

    // scaled agg^T packed pairs; linear index dt*16+r maps to group g'=idx>>2
    __bf16 agh[32], agl[32];
    #pragma unroll
    for (int r = 0; r < 16; ++r) {
        bfpair p = split1(O0[r] * linv);
        agh[r] = p.h; agl[r] = p.l;
    }
    #pragma unroll
    for (int r = 0; r < 16; ++r) {
        bfpair p = split1(O1[r] * linv);
        agh[16+r] = p.h; agl[16+r] = p.l;
    }
    unsigned AH[8][2], AL[8][2];
    #pragma unroll
    for (int gg = 0; gg < 8; ++gg) {
        AH[gg][0] = pk2(agh[4*gg],   agh[4*gg+1]);
        AH[gg][1] = pk2(agh[4*gg+2], agh[4*gg+3]);
        AL[gg][0] = pk2(agl[4*gg],   agl[4*gg+1]);
        AL[gg][1] = pk2(agl[4*gg+2], agl[4*gg+3]);
    }

    floatx16 OC0 = {}, OC1 = {};
    #pragma unroll
    for (int kc = 0; kc < 4; ++kc) {
        bf16x8 bh = xchg(AH[2*kc][0], AH[2*kc][1],
                         AH[2*kc+1][0], AH[2*kc+1][1], L5);
        bf16x8 bl = xchg(AL[2*kc][0], AL[2*kc][1],
                         AL[2*kc+1][0], AL[2*kc+1][1], L5);
        OC0 = MFMA32(th[0][kc], bh, OC0);
        OC0 = MFMA32(tlo[0][kc], bh, OC0);
        OC0 = MFMA32(th[0][kc], bl, OC0);
        OC1 = MFMA32(th[1][kc], bh, OC1);
        OC1 = MFMA32(tlo[1][kc], bh, OC1);
        OC1 = MFMA32(th[1][kc], bl, OC1);
    }

    // ---- store: out[q][o], o = ot*32 + 8*rg + 4*L5 + i, relu ----
    float* obase = out + (size_t)bb * (NNODE * XROW) + tt * ND
                       + (size_t)qglob * XROW;
    #pragma unroll
    for (int rg = 0; rg < 4; ++rg) {
        floatx4 v0, v1;
        #pragma unroll
        for (int i = 0; i < 4; ++i) {
            float a = OC0[4*rg + i]; v0[i] = a > 0.f ? a : 0.f;
            float b = OC1[4*rg + i]; v1[i] = b > 0.f ? b : 0.f;
        }
        *(floatx4*)(obase + 8*rg + 4*L5)      = v0;
        *(floatx4*)(obase + 32 + 8*rg + 4*L5) = v1;
    }
}

extern "C" void kernel_launch(void* const* d_in, const int* in_sizes, int n_in,
                              void* d_out, int out_size, void* d_ws, size_t ws_size,
                              hipStream_t stream) {
    (void)in_sizes; (void)n_in; (void)d_ws; (void)ws_size; (void)out_size;
    const float* x     = (const float*)d_in[0];
    const float* adj   = (const float*)d_in[1];
    const float* theta = (const float*)d_in[2];
    float* out = (float*)d_out;
    spattn<<<dim3(768), dim3(256), 0, stream>>>(x, adj, theta, out);
}